// Round 1
// baseline (1897.792 us; speedup 1.0000x reference)
//
#include <hip/hip_runtime.h>
#include <hip/hip_bf16.h>

// GCN layer, fused: out[i][j] = b[j] + sum_k ( sum_{e: row[e]==i} val[e]*x[col[e]][k] ) * W[j][k]
// N=50000 nodes, E=800000 edges (row sorted), D_IN=D_OUT=128, fp32.
//
// Structure:
//   - 1 block (256 thr) per tile of NPB=31 nodes.
//   - Phase 0: 32 binary searches on sorted edge_row -> per-node edge ranges (no atomics).
//              Stage W (64 KB) into LDS with float4 XOR swizzle (conflict-free b128 reads).
//   - Phase 1: 128 threads per node (one feature each), accumulate agg row into LDS.
//   - Phase 2: projection; each thread owns one output column j and 8 node-accumulators,
//              so every W float4 LDS read is reused 8x (LDS-BW control); fp32 vector FMA.
// LDS: 65536 (W) + 15872 (agg) + 128 (row_start) = 81536 B -> 2 blocks/CU.

#define NPB   31
#define BLOCK 256
#define D     128

__global__ __launch_bounds__(BLOCK, 2)
void gcn_fused_kernel(const float* __restrict__ x,
                      const int*   __restrict__ edge_row,
                      const int*   __restrict__ edge_col,
                      const float* __restrict__ edge_val,
                      const float* __restrict__ W,
                      const float* __restrict__ bvec,
                      float*       __restrict__ out,
                      int n_nodes, int n_edges)
{
    __shared__ __align__(16) float w_s[D * D];        // 64 KB, swizzled float4 layout
    __shared__ __align__(16) float agg_s[NPB * D];    // 15.5 KB
    __shared__ int rs_s[NPB + 1];                     // per-node edge range starts

    const int tid = threadIdx.x;
    const int tile_base = blockIdx.x * NPB;

    // ---- Phase 0a: binary search row starts (lower_bound over sorted edge_row) ----
    if (tid <= NPB) {
        int target = tile_base + tid;
        int lo = 0, hi = n_edges;
        while (lo < hi) {
            int mid = (lo + hi) >> 1;
            lo = (edge_row[mid] < target) ? (mid + 1) : lo;
            hi = (edge_row[mid] < target) ? hi : mid;
        }
        rs_s[tid] = lo;
    }

    // ---- Phase 0b: stage W into LDS as swizzled float4 ----
    // logical: w4[j][k4], stored at w4_s[j*32 + (k4 ^ (j&31))]
    {
        const float4* W4 = reinterpret_cast<const float4*>(W);
        float4* w4_s = reinterpret_cast<float4*>(w_s);
        #pragma unroll
        for (int idx4 = tid; idx4 < D * (D / 4); idx4 += BLOCK) {
            int j  = idx4 >> 5;        // 0..127
            int k4 = idx4 & 31;        // 0..31
            w4_s[j * 32 + (k4 ^ (j & 31))] = W4[idx4];
        }
    }
    __syncthreads();

    // ---- Phase 1: SpMM into agg_s ----
    // 128 threads per node (thread = one feature d); halves of the block work
    // on alternating nodes. 2-edge unroll, two accumulators for MLP.
    {
        const int d = tid & (D - 1);
        const int h = tid >> 7;        // 0 or 1
        for (int n = h; n < NPB; n += 2) {
            int e0 = rs_s[n], e1 = rs_s[n + 1];
            float a0 = 0.f, a1 = 0.f;
            int e = e0;
            for (; e + 2 <= e1; e += 2) {
                int   c0 = edge_col[e],     c1 = edge_col[e + 1];
                float v0 = edge_val[e],     v1 = edge_val[e + 1];
                a0 += v0 * x[(size_t)c0 * D + d];
                a1 += v1 * x[(size_t)c1 * D + d];
            }
            if (e < e1) {
                a0 += edge_val[e] * x[(size_t)edge_col[e] * D + d];
            }
            agg_s[n * D + d] = a0 + a1;
        }
    }
    __syncthreads();

    // ---- Phase 2: out[node][j] = b[j] + dot(agg[node], W[j]) ----
    // Thread owns column j; 8 node-accumulators so each w4 load is reused 8x.
    {
        const int j  = tid & (D - 1);
        const int h  = tid >> 7;               // parity of node within tile
        const int jm = j & 31;
        const float bj = bvec[j];
        const float4* w4_s  = reinterpret_cast<const float4*>(w_s);
        const float4* agg4  = reinterpret_cast<const float4*>(agg_s);

        #pragma unroll
        for (int g = 0; g < 16; g += 8) {
            float acc[8];
            #pragma unroll
            for (int r = 0; r < 8; ++r) acc[r] = 0.f;

            #pragma unroll
            for (int k4 = 0; k4 < 32; ++k4) {
                float4 w4 = w4_s[j * 32 + (k4 ^ jm)];
                #pragma unroll
                for (int r = 0; r < 8; ++r) {
                    int n  = h + 2 * (g + r);
                    int nn = (n < NPB) ? n : 0;           // clamp (discarded later)
                    float4 a4 = agg4[nn * 32 + k4];       // broadcast across wave
                    acc[r] += a4.x * w4.x + a4.y * w4.y + a4.z * w4.z + a4.w * w4.w;
                }
            }
            #pragma unroll
            for (int r = 0; r < 8; ++r) {
                int n = h + 2 * (g + r);
                int node = tile_base + n;
                if (n < NPB && node < n_nodes)
                    out[(size_t)node * D + j] = acc[r] + bj;
            }
        }
    }
}

extern "C" void kernel_launch(void* const* d_in, const int* in_sizes, int n_in,
                              void* d_out, int out_size, void* d_ws, size_t ws_size,
                              hipStream_t stream) {
    const float* x        = (const float*)d_in[0];
    const int*   edge_row = (const int*)  d_in[1];
    const int*   edge_col = (const int*)  d_in[2];
    const float* edge_val = (const float*)d_in[3];
    const float* W        = (const float*)d_in[4];
    const float* b        = (const float*)d_in[5];
    float* out = (float*)d_out;

    const int n_nodes = in_sizes[0] / D;
    const int n_edges = in_sizes[1];

    const int grid = (n_nodes + NPB - 1) / NPB;
    gcn_fused_kernel<<<grid, BLOCK, 0, stream>>>(x, edge_row, edge_col, edge_val,
                                                 W, b, out, n_nodes, n_edges);
}

// Round 2
// 249.463 us; speedup vs baseline: 7.6075x; 7.6075x over previous
//
#include <hip/hip_runtime.h>
#include <hip/hip_bf16.h>

// GCN layer, fused: out[i][j] = b[j] + sum_k ( sum_{e: row[e]==i} val[e]*x[col[e]][k] ) * W[j][k]
// N=50000 nodes, E=800000 edges (row sorted), D_IN=D_OUT=128, fp32.
//
// R2 changes vs R1 (theory: R1 was latency-bound + suspected phase-2 register
// spill producing 2.7 GB of scratch writes):
//   - Phase 1: wave-per-node, lane owns a float2 of features, 8-edge load
//     pipeline (8 independent gathers in flight per wave instead of 2),
//     predicated batch tail instead of serial scalar tail.
//   - Phase 2: accumulator blocking 8 -> 4 (live set ~24 VGPRs, no spill).
// LDS: 65536 (W) + 15872 (agg) + 128 (rs) = 81536 B -> 2 blocks/CU, 8 waves/CU.

#define NPB   31
#define BLOCK 256
#define D     128
#define PIPE  8

__global__ __launch_bounds__(BLOCK, 2)
void gcn_fused_kernel(const float* __restrict__ x,
                      const int*   __restrict__ edge_row,
                      const int*   __restrict__ edge_col,
                      const float* __restrict__ edge_val,
                      const float* __restrict__ W,
                      const float* __restrict__ bvec,
                      float*       __restrict__ out,
                      int n_nodes, int n_edges)
{
    __shared__ __align__(16) float w_s[D * D];        // 64 KB, swizzled float4 layout
    __shared__ __align__(16) float agg_s[NPB * D];    // 15.5 KB
    __shared__ int rs_s[NPB + 1];                     // per-node edge range starts

    const int tid = threadIdx.x;
    const int tile_base = blockIdx.x * NPB;

    // ---- Phase 0a: binary search row starts (lower_bound over sorted edge_row) ----
    if (tid <= NPB) {
        int target = tile_base + tid;
        int lo = 0, hi = n_edges;
        while (lo < hi) {
            int mid = (lo + hi) >> 1;
            lo = (edge_row[mid] < target) ? (mid + 1) : lo;
            hi = (edge_row[mid] < target) ? hi : mid;
        }
        rs_s[tid] = lo;
    }

    // ---- Phase 0b: stage W into LDS as swizzled float4 ----
    // logical: w4[j][k4], stored at w4_s[j*32 + (k4 ^ (j&31))]
    {
        const float4* W4 = reinterpret_cast<const float4*>(W);
        float4* w4_s = reinterpret_cast<float4*>(w_s);
        for (int idx4 = tid; idx4 < D * (D / 4); idx4 += BLOCK) {
            int j  = idx4 >> 5;        // 0..127
            int k4 = idx4 & 31;        // 0..31
            w4_s[j * 32 + (k4 ^ (j & 31))] = W4[idx4];
        }
    }
    __syncthreads();

    // ---- Phase 1: SpMM into agg_s ----
    // Wave-per-node; lane l owns features [2l, 2l+1] (float2 -> 512 B/wave/edge
    // coalesced). 8-edge pipeline: 8 independent gather loads in flight before
    // any use; tail is a predicated batch, not a serial loop.
    {
        const int wave = tid >> 6;     // 0..3
        const int lane = tid & 63;
        const size_t foff = 2 * lane;

        for (int n = wave; n < NPB; n += 4) {
            const int e0 = rs_s[n], e1 = rs_s[n + 1];
            float ax = 0.f, ay = 0.f;
            int e = e0;

            for (; e + PIPE <= e1; e += PIPE) {
                int   c[PIPE];
                float v[PIPE];
                float2 xx[PIPE];
                #pragma unroll
                for (int u = 0; u < PIPE; ++u) { c[u] = edge_col[e + u]; v[u] = edge_val[e + u]; }
                #pragma unroll
                for (int u = 0; u < PIPE; ++u) {
                    xx[u] = *reinterpret_cast<const float2*>(x + (size_t)c[u] * D + foff);
                }
                #pragma unroll
                for (int u = 0; u < PIPE; ++u) { ax += v[u] * xx[u].x; ay += v[u] * xx[u].y; }
            }

            // predicated batch tail (loads still issued together)
            {
                const int m = e1 - e;   // 0..PIPE-1
                int   c[PIPE];
                float v[PIPE];
                float2 xx[PIPE];
                #pragma unroll
                for (int u = 0; u < PIPE; ++u) {
                    c[u] = (u < m) ? edge_col[e + u] : 0;
                    v[u] = (u < m) ? edge_val[e + u] : 0.f;
                }
                #pragma unroll
                for (int u = 0; u < PIPE; ++u) {
                    if (u < m) xx[u] = *reinterpret_cast<const float2*>(x + (size_t)c[u] * D + foff);
                    else       xx[u] = make_float2(0.f, 0.f);
                }
                #pragma unroll
                for (int u = 0; u < PIPE; ++u) { ax += v[u] * xx[u].x; ay += v[u] * xx[u].y; }
            }

            *reinterpret_cast<float2*>(agg_s + n * D + foff) = make_float2(ax, ay);
        }
    }
    __syncthreads();

    // ---- Phase 2: out[node][j] = b[j] + dot(agg[node], W[j]) ----
    // Thread owns column j; 4 node-accumulators (low register pressure, W float4
    // reuse 4x). agg reads are wave-uniform broadcasts; W reads are swizzled
    // conflict-free b128.
    {
        const int j  = tid & (D - 1);
        const int h  = tid >> 7;               // parity of node within tile
        const int jm = j & 31;
        const float bj = bvec[j];
        const float4* w4_s  = reinterpret_cast<const float4*>(w_s);
        const float4* agg4  = reinterpret_cast<const float4*>(agg_s);

        #pragma unroll
        for (int g = 0; g < 16; g += 4) {
            float acc[4] = {0.f, 0.f, 0.f, 0.f};

            #pragma unroll 4
            for (int k4 = 0; k4 < 32; ++k4) {
                float4 w4 = w4_s[j * 32 + (k4 ^ jm)];
                #pragma unroll
                for (int r = 0; r < 4; ++r) {
                    int n  = h + 2 * (g + r);
                    int nn = (n < NPB) ? n : 0;           // clamp (discarded later)
                    float4 a4 = agg4[nn * 32 + k4];       // broadcast across wave
                    acc[r] += a4.x * w4.x + a4.y * w4.y + a4.z * w4.z + a4.w * w4.w;
                }
            }
            #pragma unroll
            for (int r = 0; r < 4; ++r) {
                int n = h + 2 * (g + r);
                int node = tile_base + n;
                if (n < NPB && node < n_nodes)
                    out[(size_t)node * D + j] = acc[r] + bj;
            }
        }
    }
}

extern "C" void kernel_launch(void* const* d_in, const int* in_sizes, int n_in,
                              void* d_out, int out_size, void* d_ws, size_t ws_size,
                              hipStream_t stream) {
    const float* x        = (const float*)d_in[0];
    const int*   edge_row = (const int*)  d_in[1];
    const int*   edge_col = (const int*)  d_in[2];
    const float* edge_val = (const float*)d_in[3];
    const float* W        = (const float*)d_in[4];
    const float* b        = (const float*)d_in[5];
    float* out = (float*)d_out;

    const int n_nodes = in_sizes[0] / D;
    const int n_edges = in_sizes[1];

    const int grid = (n_nodes + NPB - 1) / NPB;
    gcn_fused_kernel<<<grid, BLOCK, 0, stream>>>(x, edge_row, edge_col, edge_val,
                                                 W, b, out, n_nodes, n_edges);
}

// Round 3
// 210.914 us; speedup vs baseline: 8.9980x; 1.1828x over previous
//
#include <hip/hip_runtime.h>
#include <hip/hip_bf16.h>

// GCN layer, fused: out[i][j] = b[j] + sum_k ( sum_{e: row[e]==i} val[e]*x[col[e]][k] ) * W[j][k]
// N=50000 nodes, E=800000 edges (row sorted), D_IN=D_OUT=128, fp32.
//
// R3 changes vs R2 (theory: still gather-latency-bound at 2 blocks/CU because
// the 64 KB LDS W tile caps occupancy; W is L2-resident anyway):
//   - W no longer staged in LDS; phase 2 reads W directly (thread j walks its
//     own W row contiguously -> full L1 line reuse; agg stays an LDS broadcast).
//   - LDS drops 81.9 KB -> ~16 KB; __launch_bounds__(256,5) caps VGPRs ~102
//     -> target 5 blocks/CU (20 waves) for 2.5x latency hiding.
//   - Edge ranges readfirstlane'd -> edge_col/edge_val become SMEM s_loads
//     (uniform addresses), freeing the VMEM pipe for the x gathers.
//   - PIPE 8 -> 10 (10 independent 512 B gathers in flight per wave).

#define NPB   31
#define BLOCK 256
#define D     128
#define PIPE  10

__global__ __launch_bounds__(BLOCK, 5)
void gcn_fused_kernel(const float* __restrict__ x,
                      const int*   __restrict__ edge_row,
                      const int*   __restrict__ edge_col,
                      const float* __restrict__ edge_val,
                      const float* __restrict__ W,
                      const float* __restrict__ bvec,
                      float*       __restrict__ out,
                      int n_nodes, int n_edges)
{
    __shared__ __align__(16) float agg_s[NPB * D];    // 15.5 KB
    __shared__ int rs_s[NPB + 1];                     // per-node edge range starts

    const int tid = threadIdx.x;
    const int tile_base = blockIdx.x * NPB;

    // ---- Phase 0: binary search row starts (lower_bound over sorted edge_row) ----
    if (tid <= NPB) {
        int target = tile_base + tid;
        int lo = 0, hi = n_edges;
        while (lo < hi) {
            int mid = (lo + hi) >> 1;
            lo = (edge_row[mid] < target) ? (mid + 1) : lo;
            hi = (edge_row[mid] < target) ? hi : mid;
        }
        rs_s[tid] = lo;
    }
    __syncthreads();

    // ---- Phase 1: SpMM into agg_s ----
    // Wave-per-node; lane l owns features [2l, 2l+1] (float2 -> 512 B/wave/edge,
    // coalesced). PIPE-deep batch: all gathers issued before any use. Edge
    // ranges are readfirstlane'd so col/val loads are wave-uniform -> SMEM.
    {
        const int wave = tid >> 6;     // 0..3
        const int lane = tid & 63;
        const float* xl = x + 2 * lane;

        for (int n = wave; n < NPB; n += 4) {
            const int e0 = __builtin_amdgcn_readfirstlane(rs_s[n]);
            const int e1 = __builtin_amdgcn_readfirstlane(rs_s[n + 1]);
            float ax = 0.f, ay = 0.f;
            int e = e0;

            for (; e + PIPE <= e1; e += PIPE) {
                int   c[PIPE];
                float v[PIPE];
                float2 xx[PIPE];
                #pragma unroll
                for (int u = 0; u < PIPE; ++u) { c[u] = edge_col[e + u]; v[u] = edge_val[e + u]; }
                #pragma unroll
                for (int u = 0; u < PIPE; ++u) {
                    xx[u] = *reinterpret_cast<const float2*>(xl + ((size_t)c[u] << 7));
                }
                #pragma unroll
                for (int u = 0; u < PIPE; ++u) { ax += v[u] * xx[u].x; ay += v[u] * xx[u].y; }
            }

            // predicated batch tail (loads still issued together; m is uniform)
            {
                const int m = e1 - e;   // 0..PIPE-1
                #pragma unroll
                for (int u = 0; u < PIPE; ++u) {
                    if (u < m) {
                        int   cu = edge_col[e + u];
                        float vu = edge_val[e + u];
                        float2 xu = *reinterpret_cast<const float2*>(xl + ((size_t)cu << 7));
                        ax += vu * xu.x; ay += vu * xu.y;
                    }
                }
            }

            *reinterpret_cast<float2*>(agg_s + n * D + 2 * lane) = make_float2(ax, ay);
        }
    }
    __syncthreads();

    // ---- Phase 2: out[node][j] = b[j] + dot(agg[node], W[j]) ----
    // Thread owns column j; 8 node-accumulators per group so each W float4
    // global load is reused 8x (a4 consumed immediately -> small live set, no
    // spill). W reads: thread j walks W row j contiguously -> L1 line reuse.
    // agg reads: wave-uniform LDS broadcast (free).
    {
        const int j  = tid & (D - 1);
        const int h  = tid >> 7;               // parity of node within tile
        const float bj = bvec[j];
        const float4* W4   = reinterpret_cast<const float4*>(W);
        const float4* agg4 = reinterpret_cast<const float4*>(agg_s);

        #pragma unroll
        for (int g = 0; g < 16; g += 8) {
            float acc[8];
            #pragma unroll
            for (int r = 0; r < 8; ++r) acc[r] = 0.f;

            for (int k4 = 0; k4 < 32; ++k4) {
                float4 w4 = W4[j * 32 + k4];
                #pragma unroll
                for (int r = 0; r < 8; ++r) {
                    int n  = h + 2 * (g + r);
                    int nn = (n < NPB) ? n : 0;           // only slot 31 clamps
                    float4 a4 = agg4[nn * 32 + k4];       // broadcast across wave
                    acc[r] += a4.x * w4.x + a4.y * w4.y + a4.z * w4.z + a4.w * w4.w;
                }
            }
            #pragma unroll
            for (int r = 0; r < 8; ++r) {
                int n = h + 2 * (g + r);
                int node = tile_base + n;
                if (n < NPB && node < n_nodes)
                    out[(size_t)node * D + j] = acc[r] + bj;
            }
        }
    }
}

extern "C" void kernel_launch(void* const* d_in, const int* in_sizes, int n_in,
                              void* d_out, int out_size, void* d_ws, size_t ws_size,
                              hipStream_t stream) {
    const float* x        = (const float*)d_in[0];
    const int*   edge_row = (const int*)  d_in[1];
    const int*   edge_col = (const int*)  d_in[2];
    const float* edge_val = (const float*)d_in[3];
    const float* W        = (const float*)d_in[4];
    const float* b        = (const float*)d_in[5];
    float* out = (float*)d_out;

    const int n_nodes = in_sizes[0] / D;
    const int n_edges = in_sizes[1];

    const int grid = (n_nodes + NPB - 1) / NPB;
    gcn_fused_kernel<<<grid, BLOCK, 0, stream>>>(x, edge_row, edge_col, edge_val,
                                                 W, b, out, n_nodes, n_edges);
}

// Round 4
// 180.705 us; speedup vs baseline: 10.5022x; 1.1672x over previous
//
#include <hip/hip_runtime.h>
#include <hip/hip_bf16.h>

// GCN layer, fused: out[i][j] = b[j] + sum_k ( sum_{e: row[e]==i} val[e]*x[col[e]][k] ) * W[j][k]
// N=50000 nodes, E=800000 edges (row sorted), D_IN=D_OUT=128, fp32.
//
// R4 changes vs R3 (theory: latency-bound; serial per-edge tail dominated
// per-node time; grid too coarse for occupancy):
//   - Edge loop fully predicated: clamp index to e1-1, mask val to 0. No
//     branches, no serial tail.
//   - float4-per-lane gathers: half-wave (32 lanes x 16 B) covers one 512 B
//     x-row, so each global_load_dwordx4 serves 2 edges; 16 edges in flight
//     per 8-instruction batch. Halves combined via __shfl_xor(.,32) per node.
//   - NPB 31 -> 16 (3125 blocks, exact tiling), LDS 8.3 KB,
//     __launch_bounds__(256,6): target ~6 blocks / 24 waves per CU.
//   - Node loop fully unrolled (4 nodes/wave) for cross-node load overlap.

#define NPB   16
#define BLOCK 256
#define D     128

__global__ __launch_bounds__(BLOCK, 6)
void gcn_fused_kernel(const float* __restrict__ x,
                      const int*   __restrict__ edge_row,
                      const int*   __restrict__ edge_col,
                      const float* __restrict__ edge_val,
                      const float* __restrict__ W,
                      const float* __restrict__ bvec,
                      float*       __restrict__ out,
                      int n_nodes, int n_edges)
{
    __shared__ __align__(16) float agg_s[NPB * D];    // 8 KB
    __shared__ int rs_s[NPB + 1];

    const int tid = threadIdx.x;
    const int tile_base = blockIdx.x * NPB;

    // ---- Phase 0: binary search row starts (lower_bound over sorted edge_row) ----
    if (tid <= NPB) {
        int target = tile_base + tid;
        int lo = 0, hi = n_edges;
        while (lo < hi) {
            int mid = (lo + hi) >> 1;
            lo = (edge_row[mid] < target) ? (mid + 1) : lo;
            hi = (edge_row[mid] < target) ? hi : mid;
        }
        rs_s[tid] = lo;
    }
    __syncthreads();

    // ---- Phase 1: SpMM into agg_s ----
    // Wave-per-node; half-wave per edge: lane = (h, q), h = edge parity,
    // q = feature quad. Each batch covers 16 edges with 8 dwordx4 gathers,
    // fully predicated (no tail). Halves combined via shfl_xor(32).
    {
        const int wave = tid >> 6;     // 0..3
        const int lane = tid & 63;
        const int h = lane >> 5;       // which of the 2 edges in a pair
        const int q = lane & 31;       // feature quad: floats 4q..4q+3
        const float* xq = x + (q << 2);

        #pragma unroll
        for (int ni = 0; ni < NPB / 4; ++ni) {
            const int n = wave + 4 * ni;
            const int e0 = __builtin_amdgcn_readfirstlane(rs_s[n]);
            const int e1 = __builtin_amdgcn_readfirstlane(rs_s[n + 1]);

            float ax = 0.f, ay = 0.f, az = 0.f, aw = 0.f;

            for (int e = e0; e < e1; e += 16) {
                #pragma unroll
                for (int u = 0; u < 8; ++u) {
                    int idx  = e + 2 * u + h;
                    int idxc = (idx < e1) ? idx : (e1 - 1);    // e1>e0 here
                    int   c  = edge_col[idxc];
                    float vr = edge_val[idxc];
                    float v  = (idx < e1) ? vr : 0.f;
                    float4 xr = *reinterpret_cast<const float4*>(xq + ((size_t)c << 7));
                    ax += v * xr.x; ay += v * xr.y; az += v * xr.z; aw += v * xr.w;
                }
            }

            // combine even/odd-edge halves: lane q and lane q+32 hold partial
            // sums for features 4q..4q+3
            ax += __shfl_xor(ax, 32, 64);
            ay += __shfl_xor(ay, 32, 64);
            az += __shfl_xor(az, 32, 64);
            aw += __shfl_xor(aw, 32, 64);

            if (h == 0) {
                *reinterpret_cast<float4*>(agg_s + n * D + (q << 2)) =
                    make_float4(ax, ay, az, aw);
            }
        }
    }
    __syncthreads();

    // ---- Phase 2: out[node][j] = b[j] + dot(agg[node], W[j]) ----
    // Thread owns column j and 8 node-accumulators (all 16 tile nodes across
    // the two half-blocks). W read from global (L1/L2-resident, line reuse
    // across k4); agg read as wave-uniform LDS broadcast.
    {
        const int j  = tid & (D - 1);
        const int h2 = tid >> 7;               // node parity
        const float bj = bvec[j];
        const float4* W4   = reinterpret_cast<const float4*>(W);
        const float4* agg4 = reinterpret_cast<const float4*>(agg_s);

        float acc[8];
        #pragma unroll
        for (int r = 0; r < 8; ++r) acc[r] = 0.f;

        for (int k4 = 0; k4 < 32; ++k4) {
            float4 w4 = W4[j * 32 + k4];
            #pragma unroll
            for (int r = 0; r < 8; ++r) {
                int n = h2 + 2 * r;
                float4 a4 = agg4[n * 32 + k4];        // wave-uniform broadcast
                acc[r] += a4.x * w4.x + a4.y * w4.y + a4.z * w4.z + a4.w * w4.w;
            }
        }
        #pragma unroll
        for (int r = 0; r < 8; ++r) {
            int n = h2 + 2 * r;
            int node = tile_base + n;
            if (node < n_nodes)
                out[(size_t)node * D + j] = acc[r] + bj;
        }
    }
}

extern "C" void kernel_launch(void* const* d_in, const int* in_sizes, int n_in,
                              void* d_out, int out_size, void* d_ws, size_t ws_size,
                              hipStream_t stream) {
    const float* x        = (const float*)d_in[0];
    const int*   edge_row = (const int*)  d_in[1];
    const int*   edge_col = (const int*)  d_in[2];
    const float* edge_val = (const float*)d_in[3];
    const float* W        = (const float*)d_in[4];
    const float* b        = (const float*)d_in[5];
    float* out = (float*)d_out;

    const int n_nodes = in_sizes[0] / D;
    const int n_edges = in_sizes[1];

    const int grid = (n_nodes + NPB - 1) / NPB;
    gcn_fused_kernel<<<grid, BLOCK, 0, stream>>>(x, edge_row, edge_col, edge_val,
                                                 W, b, out, n_nodes, n_edges);
}

// Round 5
// 158.551 us; speedup vs baseline: 11.9696x; 1.1397x over previous
//
#include <hip/hip_runtime.h>
#include <hip/hip_bf16.h>

// GCN layer, fused: out[i][j] = b[j] + sum_k ( sum_{e: row[e]==i} val[e]*x[col[e]][k] ) * W[j][k]
// N=50000 nodes, E=800000 edges (row sorted), D_IN=D_OUT=128, fp32 in/out.
//
// R5 changes vs R4 (theory: phase 2 was LDS-return-bus bound — 8 broadcast
// ds_read_b128 per k4 per wave ≈ 62 µs/CU of LDS pipe time — plus ~10 µs of
// scalar-FMA VALU issue):
//   - Phase 2 is now bf16 MFMA (mfma_f32_16x16x32_bf16): M=16 nodes, N=128 j,
//     K=128. agg stored as bf16 in LDS (row stride 136 shorts = 272 B -> 2-way
//     bank aliasing = free). A-frags: 4 ds_read_b128 per wave TOTAL.
//   - W stays out of LDS: each wave loads its 2 j-tiles' B-frags once per
//     block from global (L2-hot) into registers, cvt to bf16; issued before
//     the barrier so latency overlaps the barrier wait.
//   - LDS 8.7 -> 4.4 KB; __launch_bounds__(256,5).
// Phase 1 unchanged from R4 except bf16 pack at the agg store.
// Layouts (guide-verified): A[m=lane&15][k=(lane>>4)*8+e]; B[n=lane&15][k same];
// C/D col=lane&15, row=(lane>>4)*4+reg.

#define NPB     16
#define BLOCK   256
#define D       128
#define ASTRIDE 136   // agg_s row stride in shorts (128 + 8 pad)

typedef __attribute__((ext_vector_type(8))) short bf16x8;
typedef __attribute__((ext_vector_type(4))) float f32x4;

__device__ __forceinline__ short f2bf(float f) {
    // round-to-nearest-even bf16 (finite inputs)
    unsigned u = __float_as_uint(f);
    unsigned r = (u + 0x7fffu + ((u >> 16) & 1u)) >> 16;
    return (short)r;
}

__global__ __launch_bounds__(BLOCK, 5)
void gcn_fused_kernel(const float* __restrict__ x,
                      const int*   __restrict__ edge_row,
                      const int*   __restrict__ edge_col,
                      const float* __restrict__ edge_val,
                      const float* __restrict__ W,
                      const float* __restrict__ bvec,
                      float*       __restrict__ out,
                      int n_nodes, int n_edges)
{
    __shared__ __align__(16) short agg_s[NPB * ASTRIDE];   // 4.25 KB, bf16
    __shared__ int rs_s[NPB + 1];

    const int tid  = threadIdx.x;
    const int wave = tid >> 6;     // 0..3
    const int lane = tid & 63;
    const int tile_base = blockIdx.x * NPB;

    // ---- Phase 0: binary search row starts (lower_bound over sorted edge_row) ----
    if (tid <= NPB) {
        int target = tile_base + tid;
        int lo = 0, hi = n_edges;
        while (lo < hi) {
            int mid = (lo + hi) >> 1;
            lo = (edge_row[mid] < target) ? (mid + 1) : lo;
            hi = (edge_row[mid] < target) ? hi : mid;
        }
        rs_s[tid] = lo;
    }
    __syncthreads();

    // ---- Phase 1: SpMM -> agg_s (bf16) ----
    // Wave-per-node; half-wave per edge: h = edge parity, q = feature quad.
    // 16 edges per batch via 8 dwordx4 gathers, fully predicated (no tail).
    {
        const int h = lane >> 5;       // which of the 2 edges in a pair
        const int q = lane & 31;       // feature quad: floats 4q..4q+3
        const float* xq = x + (q << 2);

        #pragma unroll
        for (int ni = 0; ni < NPB / 4; ++ni) {
            const int n = wave + 4 * ni;
            const int e0 = __builtin_amdgcn_readfirstlane(rs_s[n]);
            const int e1 = __builtin_amdgcn_readfirstlane(rs_s[n + 1]);

            float ax = 0.f, ay = 0.f, az = 0.f, aw = 0.f;

            for (int e = e0; e < e1; e += 16) {
                #pragma unroll
                for (int u = 0; u < 8; ++u) {
                    int idx  = e + 2 * u + h;
                    int idxc = (idx < e1) ? idx : (e1 - 1);    // e1 > e0 here
                    int   c  = edge_col[idxc];
                    float vr = edge_val[idxc];
                    float v  = (idx < e1) ? vr : 0.f;
                    float4 xr = *reinterpret_cast<const float4*>(xq + ((size_t)c << 7));
                    ax += v * xr.x; ay += v * xr.y; az += v * xr.z; aw += v * xr.w;
                }
            }

            ax += __shfl_xor(ax, 32, 64);
            ay += __shfl_xor(ay, 32, 64);
            az += __shfl_xor(az, 32, 64);
            aw += __shfl_xor(aw, 32, 64);

            if (h == 0) {
                *reinterpret_cast<short4*>(&agg_s[n * ASTRIDE + (q << 2)]) =
                    make_short4(f2bf(ax), f2bf(ay), f2bf(az), f2bf(aw));
            }
        }
    }

    // ---- B-fragment load (W, global->reg, cvt bf16) — before the barrier so
    // the L2-hot load latency overlaps the barrier wait. Wave w owns j-tiles
    // {2w, 2w+1}; lane = (n16 = j within tile, g = k-group).
    const int n16 = lane & 15;
    const int g   = lane >> 4;     // 0..3

    bf16x8 bfr[2][4];
    #pragma unroll
    for (int t = 0; t < 2; ++t) {
        const int jt = 2 * wave + t;
        const float* rowp = W + ((size_t)(jt * 16 + n16)) * D + g * 8;
        #pragma unroll
        for (int ks = 0; ks < 4; ++ks) {
            float4 wa = *reinterpret_cast<const float4*>(rowp + ks * 32);
            float4 wb = *reinterpret_cast<const float4*>(rowp + ks * 32 + 4);
            bf16x8 f;
            f[0] = f2bf(wa.x); f[1] = f2bf(wa.y); f[2] = f2bf(wa.z); f[3] = f2bf(wa.w);
            f[4] = f2bf(wb.x); f[5] = f2bf(wb.y); f[6] = f2bf(wb.z); f[7] = f2bf(wb.w);
            bfr[t][ks] = f;
        }
    }

    __syncthreads();

    // ---- Phase 2: out = agg @ W^T + b via MFMA ----
    {
        // A-fragments: m = lane&15 (node), k = ks*32 + g*8 + e
        bf16x8 afr[4];
        #pragma unroll
        for (int ks = 0; ks < 4; ++ks) {
            afr[ks] = *reinterpret_cast<const bf16x8*>(
                &agg_s[n16 * ASTRIDE + ks * 32 + g * 8]);
        }

        #pragma unroll
        for (int t = 0; t < 2; ++t) {
            const int jt = 2 * wave + t;
            const int j  = jt * 16 + n16;
            const float bj = bvec[j];

            f32x4 acc = {0.f, 0.f, 0.f, 0.f};
            #pragma unroll
            for (int ks = 0; ks < 4; ++ks) {
                acc = __builtin_amdgcn_mfma_f32_16x16x32_bf16(afr[ks], bfr[t][ks], acc, 0, 0, 0);
            }

            #pragma unroll
            for (int r = 0; r < 4; ++r) {
                int node = tile_base + g * 4 + r;     // row = (lane>>4)*4 + reg
                if (node < n_nodes)
                    out[(size_t)node * D + j] = acc[r] + bj;
            }
        }
    }
}

extern "C" void kernel_launch(void* const* d_in, const int* in_sizes, int n_in,
                              void* d_out, int out_size, void* d_ws, size_t ws_size,
                              hipStream_t stream) {
    const float* x        = (const float*)d_in[0];
    const int*   edge_row = (const int*)  d_in[1];
    const int*   edge_col = (const int*)  d_in[2];
    const float* edge_val = (const float*)d_in[3];
    const float* W        = (const float*)d_in[4];
    const float* b        = (const float*)d_in[5];
    float* out = (float*)d_out;

    const int n_nodes = in_sizes[0] / D;
    const int n_edges = in_sizes[1];

    const int grid = (n_nodes + NPB - 1) / NPB;
    gcn_fused_kernel<<<grid, BLOCK, 0, stream>>>(x, edge_row, edge_col, edge_val,
                                                 W, b, out, n_nodes, n_edges);
}

// Round 6
// 149.908 us; speedup vs baseline: 12.6598x; 1.0577x over previous
//
#include <hip/hip_runtime.h>
#include <hip/hip_bf16.h>

// GCN layer, fused: out[i][j] = b[j] + sum_k ( sum_{e: row[e]==i} val[e]*x[col[e]][k] ) * W[j][k]
// N=50000 nodes, E=800000 edges (row sorted), D_IN=D_OUT=128, fp32 in/out.
//
// R6 changes vs R5 (theory: phase 1 gather is the whole kernel now; 410 MB of
// fp32 row gathers through L2/L3 + a col->gather chained global latency):
//   - Pre-pass converts x to bf16 into d_ws (12.8 MB): gather traffic halves
//     to 205 MB and bf16-x is closer to L2/L3-resident.
//   - bf16 rows are 256 B -> quarter-wave (16 lanes x 16 B) per edge: one
//     dwordx4 serves 4 edges; each quarter-wave owns its own node -> no
//     cross-lane reduction at all.
//   - Block's edge range is contiguous (row-sorted): stage (col,val) pairs
//     into LDS coalesced, so the per-edge metadata read is a ~6 cyc ds_read
//     instead of a chained global load.
//   - Phase 2 (MFMA, verified in R5) unchanged.
//   - Fallback: if ws_size < 12.8 MB, launch the R5 fp32-gather kernel.

#define NPB     16
#define BLOCK   256
#define D       128
#define CHUNK   512
#define ASTRIDE 136   // agg_s row stride in shorts (128 + 8 pad)

typedef __attribute__((ext_vector_type(8))) short bf16x8;
typedef __attribute__((ext_vector_type(4))) float f32x4;

__device__ __forceinline__ short f2bf(float f) {
    unsigned u = __float_as_uint(f);
    unsigned r = (u + 0x7fffu + ((u >> 16) & 1u)) >> 16;
    return (short)r;
}
__device__ __forceinline__ float bf_lo(int w) { return __int_as_float(w << 16); }
__device__ __forceinline__ float bf_hi(int w) { return __int_as_float(w & 0xffff0000); }

// ---------------- pre-pass: x fp32 -> bf16 ----------------
__global__ __launch_bounds__(256)
void cvt_x_kernel(const float* __restrict__ x, short* __restrict__ xb, int n4) {
    int i = blockIdx.x * 256 + threadIdx.x;
    if (i < n4) {
        float4 v = reinterpret_cast<const float4*>(x)[i];
        short4 o = make_short4(f2bf(v.x), f2bf(v.y), f2bf(v.z), f2bf(v.w));
        reinterpret_cast<short4*>(xb)[i] = o;
    }
}

// ---------------- main kernel (bf16 x in ws) ----------------
__global__ __launch_bounds__(BLOCK, 6)
void gcn_main_kernel(const short* __restrict__ xb,
                     const int*   __restrict__ edge_row,
                     const int*   __restrict__ edge_col,
                     const float* __restrict__ edge_val,
                     const float* __restrict__ W,
                     const float* __restrict__ bvec,
                     float*       __restrict__ out,
                     int n_nodes, int n_edges)
{
    __shared__ int2  cv_s[CHUNK];             // (col, val bits), 4 KB
    __shared__ __align__(16) short agg_s[NPB * ASTRIDE];   // 4.25 KB bf16
    __shared__ int rs_s[NPB + 1];

    const int tid  = threadIdx.x;
    const int wave = tid >> 6;
    const int lane = tid & 63;
    const int tile_base = blockIdx.x * NPB;

    // ---- Phase 0: binary search row starts ----
    if (tid <= NPB) {
        int target = tile_base + tid;
        if (target > n_nodes) target = n_nodes;
        int lo = 0, hi = n_edges;
        while (lo < hi) {
            int mid = (lo + hi) >> 1;
            lo = (edge_row[mid] < target) ? (mid + 1) : lo;
            hi = (edge_row[mid] < target) ? hi : mid;
        }
        rs_s[tid] = lo;
    }
    __syncthreads();

    const int E0 = __builtin_amdgcn_readfirstlane(rs_s[0]);
    const int E1 = __builtin_amdgcn_readfirstlane(rs_s[NPB]);

    // ---- Phase 1: quarter-wave-per-node bf16 SpMM ----
    const int p = lane >> 4;            // quarter-wave id -> node within wave
    const int q = lane & 15;            // feature oct (8 bf16 = 16 B)
    const int n = wave * 4 + p;         // node within tile
    const int e0 = rs_s[n], e1 = rs_s[n + 1];
    const short* xq = xb + q * 8;

    float acc[8];
    #pragma unroll
    for (int i = 0; i < 8; ++i) acc[i] = 0.f;

    for (int cb = E0; cb < E1; cb += CHUNK) {
        const int cnt = min(E1 - cb, CHUNK);
        __syncthreads();                // protect cv_s across chunks
        for (int i = tid; i < cnt; i += BLOCK) {
            cv_s[i] = make_int2(edge_col[cb + i], __float_as_int(edge_val[cb + i]));
        }
        __syncthreads();

        const int s = max(e0, cb);
        const int t = min(e1, cb + cnt);
        int m = t - s;                  // edges of my node in this chunk (may be <=0)
        int mm = max(m, __shfl_xor(m, 16, 64));
        mm = max(mm, __shfl_xor(mm, 32, 64));
        mm = __builtin_amdgcn_readfirstlane(mm);

        for (int it = 0; it < mm; it += 4) {
            #pragma unroll
            for (int u = 0; u < 4; ++u) {
                int idx = s + it + u;
                bool ok = (idx < t);
                int il = idx - cb;
                il = ok ? il : 0;
                int2 cv = cv_s[il];
                float v = ok ? __int_as_float(cv.y) : 0.f;
                int4 xr = *reinterpret_cast<const int4*>(xq + ((size_t)cv.x << 7));
                acc[0] += v * bf_lo(xr.x); acc[1] += v * bf_hi(xr.x);
                acc[2] += v * bf_lo(xr.y); acc[3] += v * bf_hi(xr.y);
                acc[4] += v * bf_lo(xr.z); acc[5] += v * bf_hi(xr.z);
                acc[6] += v * bf_lo(xr.w); acc[7] += v * bf_hi(xr.w);
            }
        }
    }

    // store agg row segment (each lane owns node n, features 8q..8q+7)
    {
        bf16x8 o;
        #pragma unroll
        for (int i = 0; i < 8; ++i) o[i] = f2bf(acc[i]);
        *reinterpret_cast<bf16x8*>(&agg_s[n * ASTRIDE + q * 8]) = o;
    }

    // ---- B-fragment load (W global->reg, cvt bf16) before the barrier ----
    const int n16 = lane & 15;
    const int g   = lane >> 4;

    bf16x8 bfr[2][4];
    #pragma unroll
    for (int tt = 0; tt < 2; ++tt) {
        const int jt = 2 * wave + tt;
        const float* rowp = W + ((size_t)(jt * 16 + n16)) * D + g * 8;
        #pragma unroll
        for (int ks = 0; ks < 4; ++ks) {
            float4 wa = *reinterpret_cast<const float4*>(rowp + ks * 32);
            float4 wb = *reinterpret_cast<const float4*>(rowp + ks * 32 + 4);
            bf16x8 f;
            f[0] = f2bf(wa.x); f[1] = f2bf(wa.y); f[2] = f2bf(wa.z); f[3] = f2bf(wa.w);
            f[4] = f2bf(wb.x); f[5] = f2bf(wb.y); f[6] = f2bf(wb.z); f[7] = f2bf(wb.w);
            bfr[tt][ks] = f;
        }
    }

    __syncthreads();

    // ---- Phase 2: out = agg @ W^T + b via MFMA (layout verified in R5) ----
    {
        bf16x8 afr[4];
        #pragma unroll
        for (int ks = 0; ks < 4; ++ks) {
            afr[ks] = *reinterpret_cast<const bf16x8*>(
                &agg_s[n16 * ASTRIDE + ks * 32 + g * 8]);
        }

        #pragma unroll
        for (int tt = 0; tt < 2; ++tt) {
            const int jt = 2 * wave + tt;
            const int j  = jt * 16 + n16;
            const float bj = bvec[j];

            f32x4 c = {0.f, 0.f, 0.f, 0.f};
            #pragma unroll
            for (int ks = 0; ks < 4; ++ks) {
                c = __builtin_amdgcn_mfma_f32_16x16x32_bf16(afr[ks], bfr[tt][ks], c, 0, 0, 0);
            }
            #pragma unroll
            for (int r = 0; r < 4; ++r) {
                int node = tile_base + g * 4 + r;
                if (node < n_nodes)
                    out[(size_t)node * D + j] = c[r] + bj;
            }
        }
    }
}

// ---------------- fallback (R5 kernel, fp32 gathers, no ws) ----------------
__global__ __launch_bounds__(BLOCK, 5)
void gcn_fallback_kernel(const float* __restrict__ x,
                         const int*   __restrict__ edge_row,
                         const int*   __restrict__ edge_col,
                         const float* __restrict__ edge_val,
                         const float* __restrict__ W,
                         const float* __restrict__ bvec,
                         float*       __restrict__ out,
                         int n_nodes, int n_edges)
{
    __shared__ __align__(16) short agg_s[NPB * ASTRIDE];
    __shared__ int rs_s[NPB + 1];

    const int tid  = threadIdx.x;
    const int wave = tid >> 6;
    const int lane = tid & 63;
    const int tile_base = blockIdx.x * NPB;

    if (tid <= NPB) {
        int target = tile_base + tid;
        if (target > n_nodes) target = n_nodes;
        int lo = 0, hi = n_edges;
        while (lo < hi) {
            int mid = (lo + hi) >> 1;
            lo = (edge_row[mid] < target) ? (mid + 1) : lo;
            hi = (edge_row[mid] < target) ? hi : mid;
        }
        rs_s[tid] = lo;
    }
    __syncthreads();

    {
        const int h = lane >> 5;
        const int q = lane & 31;
        const float* xq = x + (q << 2);

        #pragma unroll
        for (int ni = 0; ni < NPB / 4; ++ni) {
            const int n = wave + 4 * ni;
            const int e0 = __builtin_amdgcn_readfirstlane(rs_s[n]);
            const int e1 = __builtin_amdgcn_readfirstlane(rs_s[n + 1]);
            float ax = 0.f, ay = 0.f, az = 0.f, aw = 0.f;
            for (int e = e0; e < e1; e += 16) {
                #pragma unroll
                for (int u = 0; u < 8; ++u) {
                    int idx  = e + 2 * u + h;
                    int idxc = (idx < e1) ? idx : (e1 - 1);
                    int   c  = edge_col[idxc];
                    float vr = edge_val[idxc];
                    float v  = (idx < e1) ? vr : 0.f;
                    float4 xr = *reinterpret_cast<const float4*>(xq + ((size_t)c << 7));
                    ax += v * xr.x; ay += v * xr.y; az += v * xr.z; aw += v * xr.w;
                }
            }
            ax += __shfl_xor(ax, 32, 64); ay += __shfl_xor(ay, 32, 64);
            az += __shfl_xor(az, 32, 64); aw += __shfl_xor(aw, 32, 64);
            if (h == 0) {
                *reinterpret_cast<short4*>(&agg_s[n * ASTRIDE + (q << 2)]) =
                    make_short4(f2bf(ax), f2bf(ay), f2bf(az), f2bf(aw));
            }
        }
    }

    const int n16 = lane & 15;
    const int g   = lane >> 4;
    bf16x8 bfr[2][4];
    #pragma unroll
    for (int tt = 0; tt < 2; ++tt) {
        const int jt = 2 * wave + tt;
        const float* rowp = W + ((size_t)(jt * 16 + n16)) * D + g * 8;
        #pragma unroll
        for (int ks = 0; ks < 4; ++ks) {
            float4 wa = *reinterpret_cast<const float4*>(rowp + ks * 32);
            float4 wb = *reinterpret_cast<const float4*>(rowp + ks * 32 + 4);
            bf16x8 f;
            f[0] = f2bf(wa.x); f[1] = f2bf(wa.y); f[2] = f2bf(wa.z); f[3] = f2bf(wa.w);
            f[4] = f2bf(wb.x); f[5] = f2bf(wb.y); f[6] = f2bf(wb.z); f[7] = f2bf(wb.w);
            bfr[tt][ks] = f;
        }
    }
    __syncthreads();
    {
        bf16x8 afr[4];
        #pragma unroll
        for (int ks = 0; ks < 4; ++ks)
            afr[ks] = *reinterpret_cast<const bf16x8*>(&agg_s[n16 * ASTRIDE + ks * 32 + g * 8]);
        #pragma unroll
        for (int tt = 0; tt < 2; ++tt) {
            const int jt = 2 * wave + tt;
            const int j  = jt * 16 + n16;
            const float bj = bvec[j];
            f32x4 c = {0.f, 0.f, 0.f, 0.f};
            #pragma unroll
            for (int ks = 0; ks < 4; ++ks)
                c = __builtin_amdgcn_mfma_f32_16x16x32_bf16(afr[ks], bfr[tt][ks], c, 0, 0, 0);
            #pragma unroll
            for (int r = 0; r < 4; ++r) {
                int node = tile_base + g * 4 + r;
                if (node < n_nodes)
                    out[(size_t)node * D + j] = c[r] + bj;
            }
        }
    }
}

extern "C" void kernel_launch(void* const* d_in, const int* in_sizes, int n_in,
                              void* d_out, int out_size, void* d_ws, size_t ws_size,
                              hipStream_t stream) {
    const float* x        = (const float*)d_in[0];
    const int*   edge_row = (const int*)  d_in[1];
    const int*   edge_col = (const int*)  d_in[2];
    const float* edge_val = (const float*)d_in[3];
    const float* W        = (const float*)d_in[4];
    const float* b        = (const float*)d_in[5];
    float* out = (float*)d_out;

    const int n_nodes = in_sizes[0] / D;
    const int n_edges = in_sizes[1];
    const int grid = (n_nodes + NPB - 1) / NPB;

    const size_t need = (size_t)n_nodes * D * sizeof(short);
    if (ws_size >= need) {
        short* xb = (short*)d_ws;
        const int n4 = n_nodes * D / 4;
        cvt_x_kernel<<<(n4 + 255) / 256, 256, 0, stream>>>(x, xb, n4);
        gcn_main_kernel<<<grid, BLOCK, 0, stream>>>(xb, edge_row, edge_col, edge_val,
                                                    W, b, out, n_nodes, n_edges);
    } else {
        gcn_fallback_kernel<<<grid, BLOCK, 0, stream>>>(x, edge_row, edge_col, edge_val,
                                                        W, b, out, n_nodes, n_edges);
    }
}

// Round 7
// 138.380 us; speedup vs baseline: 13.7144x; 1.0833x over previous
//
#include <hip/hip_runtime.h>
#include <hip/hip_bf16.h>

// GCN layer, fused: out[i][j] = b[j] + sum_k ( sum_{e: row[e]==i} val[e]*x[col[e]][k] ) * W[j][k]
// N=50000 nodes, E=800000 edges (row sorted), D_IN=D_OUT=128, fp32 in/out.
//
// R7 changes vs R6 (theory: per-block serial latency chains dominate; the
// 20-deep binary search (~8-15K cyc, one wave working, three waiting) is now
// the longest serial segment of each block):
//   - Prepass computes ALL 50001 CSR row starts (parallel binary searches,
//     ordered first in the grid) fused with the x->bf16 conversion. Main
//     kernel phase 0 is one coalesced 17-int load.
//   - Phase-1 gather unroll 4 -> 8: 8 independent gathers in flight per
//     quarter-wave, ~3 latency round-trips per chunk instead of ~6.
//   - Everything else (LDS edge staging, quarter-wave bf16 gathers, MFMA
//     phase 2 — verified R5/R6) unchanged.
//   - Fallback to the R5-style fp32 kernel if ws too small.

#define NPB     16
#define BLOCK   256
#define D       128
#define CHUNK   512
#define ASTRIDE 136   // agg_s row stride in shorts (128 + 8 pad)

typedef __attribute__((ext_vector_type(8))) short bf16x8;
typedef __attribute__((ext_vector_type(4))) float f32x4;

__device__ __forceinline__ short f2bf(float f) {
    unsigned u = __float_as_uint(f);
    unsigned r = (u + 0x7fffu + ((u >> 16) & 1u)) >> 16;
    return (short)r;
}
__device__ __forceinline__ float bf_lo(int w) { return __int_as_float(w << 16); }
__device__ __forceinline__ float bf_hi(int w) { return __int_as_float(w & 0xffff0000); }

// ---------------- prepass: row-pointer build + x fp32->bf16 ----------------
// Thread ids [0, n_nodes] do one lower_bound each (long-latency chains, put
// first so they overlap the streaming cvt); ids beyond that convert one
// float4 of x each.
__global__ __launch_bounds__(256)
void prepass_kernel(const float* __restrict__ x,
                    const int*   __restrict__ edge_row,
                    short* __restrict__ xb,
                    int*   __restrict__ rs,
                    int n_nodes, int n_edges, int n4)
{
    const int gid = blockIdx.x * 256 + threadIdx.x;

    if (gid <= n_nodes) {
        int lo = 0, hi = n_edges;
        while (lo < hi) {
            int mid = (lo + hi) >> 1;
            bool lt = (edge_row[mid] < gid);
            lo = lt ? (mid + 1) : lo;
            hi = lt ? hi : mid;
        }
        rs[gid] = lo;
    }

    const int i = gid - (n_nodes + 1);
    if (i >= 0 && i < n4) {
        float4 v = reinterpret_cast<const float4*>(x)[i];
        reinterpret_cast<short4*>(xb)[i] =
            make_short4(f2bf(v.x), f2bf(v.y), f2bf(v.z), f2bf(v.w));
    }
}

// ---------------- main kernel (bf16 x + precomputed rs in ws) ----------------
__global__ __launch_bounds__(BLOCK, 6)
void gcn_main_kernel(const short* __restrict__ xb,
                     const int*   __restrict__ rs_g,
                     const int*   __restrict__ edge_col,
                     const float* __restrict__ edge_val,
                     const float* __restrict__ W,
                     const float* __restrict__ bvec,
                     float*       __restrict__ out,
                     int n_nodes, int n_edges)
{
    __shared__ int2  cv_s[CHUNK];                          // 4 KB
    __shared__ __align__(16) short agg_s[NPB * ASTRIDE];   // 4.25 KB bf16
    __shared__ int rs_s[NPB + 1];

    const int tid  = threadIdx.x;
    const int wave = tid >> 6;
    const int lane = tid & 63;
    const int tile_base = blockIdx.x * NPB;

    // ---- Phase 0: load precomputed row starts (one coalesced read) ----
    if (tid <= NPB) rs_s[tid] = rs_g[tile_base + tid];
    __syncthreads();

    const int E0 = __builtin_amdgcn_readfirstlane(rs_s[0]);
    const int E1 = __builtin_amdgcn_readfirstlane(rs_s[NPB]);

    // ---- Phase 1: quarter-wave-per-node bf16 SpMM ----
    const int p = lane >> 4;            // quarter-wave id -> node within wave
    const int q = lane & 15;            // feature oct (8 bf16 = 16 B)
    const int n = wave * 4 + p;         // node within tile
    const int e0 = rs_s[n], e1 = rs_s[n + 1];
    const short* xq = xb + q * 8;

    float acc[8];
    #pragma unroll
    for (int i = 0; i < 8; ++i) acc[i] = 0.f;

    for (int cb = E0; cb < E1; cb += CHUNK) {
        const int cnt = min(E1 - cb, CHUNK);
        __syncthreads();                // protect cv_s across chunks
        for (int i = tid; i < cnt; i += BLOCK) {
            cv_s[i] = make_int2(edge_col[cb + i], __float_as_int(edge_val[cb + i]));
        }
        __syncthreads();

        const int s = max(e0, cb);
        const int t = min(e1, cb + cnt);
        int m = t - s;                  // my node's edges in this chunk (may be <=0)
        int mm = max(m, __shfl_xor(m, 16, 64));
        mm = max(mm, __shfl_xor(mm, 32, 64));
        mm = __builtin_amdgcn_readfirstlane(mm);

        for (int it = 0; it < mm; it += 8) {
            #pragma unroll
            for (int u = 0; u < 8; ++u) {
                int idx = s + it + u;
                bool ok = (idx < t);
                int il = ok ? (idx - cb) : 0;
                int2 cv = cv_s[il];
                float v = ok ? __int_as_float(cv.y) : 0.f;
                int4 xr = *reinterpret_cast<const int4*>(xq + ((size_t)cv.x << 7));
                acc[0] += v * bf_lo(xr.x); acc[1] += v * bf_hi(xr.x);
                acc[2] += v * bf_lo(xr.y); acc[3] += v * bf_hi(xr.y);
                acc[4] += v * bf_lo(xr.z); acc[5] += v * bf_hi(xr.z);
                acc[6] += v * bf_lo(xr.w); acc[7] += v * bf_hi(xr.w);
            }
        }
    }

    // store agg row segment (lane owns node n, features 8q..8q+7)
    {
        bf16x8 o;
        #pragma unroll
        for (int i = 0; i < 8; ++i) o[i] = f2bf(acc[i]);
        *reinterpret_cast<bf16x8*>(&agg_s[n * ASTRIDE + q * 8]) = o;
    }

    // ---- B-fragment load (W global->reg, cvt bf16) before the barrier ----
    const int n16 = lane & 15;
    const int g   = lane >> 4;

    bf16x8 bfr[2][4];
    #pragma unroll
    for (int tt = 0; tt < 2; ++tt) {
        const int jt = 2 * wave + tt;
        const float* rowp = W + ((size_t)(jt * 16 + n16)) * D + g * 8;
        #pragma unroll
        for (int ks = 0; ks < 4; ++ks) {
            float4 wa = *reinterpret_cast<const float4*>(rowp + ks * 32);
            float4 wb = *reinterpret_cast<const float4*>(rowp + ks * 32 + 4);
            bf16x8 f;
            f[0] = f2bf(wa.x); f[1] = f2bf(wa.y); f[2] = f2bf(wa.z); f[3] = f2bf(wa.w);
            f[4] = f2bf(wb.x); f[5] = f2bf(wb.y); f[6] = f2bf(wb.z); f[7] = f2bf(wb.w);
            bfr[tt][ks] = f;
        }
    }

    __syncthreads();

    // ---- Phase 2: out = agg @ W^T + b via MFMA (layout verified R5/R6) ----
    {
        bf16x8 afr[4];
        #pragma unroll
        for (int ks = 0; ks < 4; ++ks) {
            afr[ks] = *reinterpret_cast<const bf16x8*>(
                &agg_s[n16 * ASTRIDE + ks * 32 + g * 8]);
        }

        #pragma unroll
        for (int tt = 0; tt < 2; ++tt) {
            const int jt = 2 * wave + tt;
            const int j  = jt * 16 + n16;
            const float bj = bvec[j];

            f32x4 c = {0.f, 0.f, 0.f, 0.f};
            #pragma unroll
            for (int ks = 0; ks < 4; ++ks) {
                c = __builtin_amdgcn_mfma_f32_16x16x32_bf16(afr[ks], bfr[tt][ks], c, 0, 0, 0);
            }
            #pragma unroll
            for (int r = 0; r < 4; ++r) {
                int node = tile_base + g * 4 + r;
                if (node < n_nodes)
                    out[(size_t)node * D + j] = c[r] + bj;
            }
        }
    }
}

// ---------------- fallback (R5 kernel, fp32 gathers, no ws) ----------------
__global__ __launch_bounds__(BLOCK, 5)
void gcn_fallback_kernel(const float* __restrict__ x,
                         const int*   __restrict__ edge_row,
                         const int*   __restrict__ edge_col,
                         const float* __restrict__ edge_val,
                         const float* __restrict__ W,
                         const float* __restrict__ bvec,
                         float*       __restrict__ out,
                         int n_nodes, int n_edges)
{
    __shared__ __align__(16) short agg_s[NPB * ASTRIDE];
    __shared__ int rs_s[NPB + 1];

    const int tid  = threadIdx.x;
    const int wave = tid >> 6;
    const int lane = tid & 63;
    const int tile_base = blockIdx.x * NPB;

    if (tid <= NPB) {
        int target = tile_base + tid;
        if (target > n_nodes) target = n_nodes;
        int lo = 0, hi = n_edges;
        while (lo < hi) {
            int mid = (lo + hi) >> 1;
            lo = (edge_row[mid] < target) ? (mid + 1) : lo;
            hi = (edge_row[mid] < target) ? hi : mid;
        }
        rs_s[tid] = lo;
    }
    __syncthreads();

    {
        const int h = lane >> 5;
        const int q = lane & 31;
        const float* xq = x + (q << 2);

        #pragma unroll
        for (int ni = 0; ni < NPB / 4; ++ni) {
            const int n = wave + 4 * ni;
            const int e0 = __builtin_amdgcn_readfirstlane(rs_s[n]);
            const int e1 = __builtin_amdgcn_readfirstlane(rs_s[n + 1]);
            float ax = 0.f, ay = 0.f, az = 0.f, aw = 0.f;
            for (int e = e0; e < e1; e += 16) {
                #pragma unroll
                for (int u = 0; u < 8; ++u) {
                    int idx  = e + 2 * u + h;
                    int idxc = (idx < e1) ? idx : (e1 - 1);
                    int   c  = edge_col[idxc];
                    float vr = edge_val[idxc];
                    float v  = (idx < e1) ? vr : 0.f;
                    float4 xr = *reinterpret_cast<const float4*>(xq + ((size_t)c << 7));
                    ax += v * xr.x; ay += v * xr.y; az += v * xr.z; aw += v * xr.w;
                }
            }
            ax += __shfl_xor(ax, 32, 64); ay += __shfl_xor(ay, 32, 64);
            az += __shfl_xor(az, 32, 64); aw += __shfl_xor(aw, 32, 64);
            if (h == 0) {
                *reinterpret_cast<short4*>(&agg_s[n * ASTRIDE + (q << 2)]) =
                    make_short4(f2bf(ax), f2bf(ay), f2bf(az), f2bf(aw));
            }
        }
    }

    const int n16 = lane & 15;
    const int g   = lane >> 4;
    bf16x8 bfr[2][4];
    #pragma unroll
    for (int tt = 0; tt < 2; ++tt) {
        const int jt = 2 * wave + tt;
        const float* rowp = W + ((size_t)(jt * 16 + n16)) * D + g * 8;
        #pragma unroll
        for (int ks = 0; ks < 4; ++ks) {
            float4 wa = *reinterpret_cast<const float4*>(rowp + ks * 32);
            float4 wb = *reinterpret_cast<const float4*>(rowp + ks * 32 + 4);
            bf16x8 f;
            f[0] = f2bf(wa.x); f[1] = f2bf(wa.y); f[2] = f2bf(wa.z); f[3] = f2bf(wa.w);
            f[4] = f2bf(wb.x); f[5] = f2bf(wb.y); f[6] = f2bf(wb.z); f[7] = f2bf(wb.w);
            bfr[tt][ks] = f;
        }
    }
    __syncthreads();
    {
        bf16x8 afr[4];
        #pragma unroll
        for (int ks = 0; ks < 4; ++ks)
            afr[ks] = *reinterpret_cast<const bf16x8*>(&agg_s[n16 * ASTRIDE + ks * 32 + g * 8]);
        #pragma unroll
        for (int tt = 0; tt < 2; ++tt) {
            const int jt = 2 * wave + tt;
            const int j  = jt * 16 + n16;
            const float bj = bvec[j];
            f32x4 c = {0.f, 0.f, 0.f, 0.f};
            #pragma unroll
            for (int ks = 0; ks < 4; ++ks)
                c = __builtin_amdgcn_mfma_f32_16x16x32_bf16(afr[ks], bfr[tt][ks], c, 0, 0, 0);
            #pragma unroll
            for (int r = 0; r < 4; ++r) {
                int node = tile_base + g * 4 + r;
                if (node < n_nodes)
                    out[(size_t)node * D + j] = c[r] + bj;
            }
        }
    }
}

extern "C" void kernel_launch(void* const* d_in, const int* in_sizes, int n_in,
                              void* d_out, int out_size, void* d_ws, size_t ws_size,
                              hipStream_t stream) {
    const float* x        = (const float*)d_in[0];
    const int*   edge_row = (const int*)  d_in[1];
    const int*   edge_col = (const int*)  d_in[2];
    const float* edge_val = (const float*)d_in[3];
    const float* W        = (const float*)d_in[4];
    const float* b        = (const float*)d_in[5];
    float* out = (float*)d_out;

    const int n_nodes = in_sizes[0] / D;
    const int n_edges = in_sizes[1];
    const int grid = (n_nodes + NPB - 1) / NPB;

    const size_t xb_bytes = (size_t)n_nodes * D * sizeof(short);
    const size_t rs_bytes = (size_t)(n_nodes + 1) * sizeof(int);
    if (ws_size >= xb_bytes + rs_bytes) {
        short* xb = (short*)d_ws;
        int*   rs = (int*)((char*)d_ws + xb_bytes);
        const int n4 = n_nodes * D / 4;
        const int total = (n_nodes + 1) + n4;
        prepass_kernel<<<(total + 255) / 256, 256, 0, stream>>>(
            x, edge_row, xb, rs, n_nodes, n_edges, n4);
        gcn_main_kernel<<<grid, BLOCK, 0, stream>>>(xb, rs, edge_col, edge_val,
                                                    W, b, out, n_nodes, n_edges);
    } else {
        gcn_fallback_kernel<<<grid, BLOCK, 0, stream>>>(x, edge_row, edge_col, edge_val,
                                                        W, b, out, n_nodes, n_edges);
    }
}

// Round 8
// 127.943 us; speedup vs baseline: 14.8331x; 1.0816x over previous
//
#include <hip/hip_runtime.h>
#include <hip/hip_bf16.h>

// GCN layer, fused: out[i][j] = b[j] + sum_k ( sum_{e: row[e]==i} val[e]*x[col[e]][k] ) * W[j][k]
// N=50000 nodes, E=800000 edges (row sorted), D_IN=D_OUT=128, fp32 in/out.
//
// R8 changes vs R7 (theory: 70% of cycles are memory waiting; W B-frag reload
// was 200 MB of L2 traffic + ~192 f2bf insts/thread per block; residency may
// be capped below the 8 blocks/CU that VGPR=40 permits):
//   - Prepass also converts W -> bf16 (wb, 32 KB in ws): B-frags become direct
//     16-B loads, W L2 traffic halves, per-block cvt VALU deleted.
//   - __launch_bounds__(256,8): explicitly allow 8 blocks/CU. Occupancy delta
//     is the discriminator between residency-cap and queueing theories.
//   - float2-packed accumulators (invites v_pk_fma_f32; safe if not taken).
// Everything else (LDS edge staging, quarter-wave bf16 gathers, MFMA phase 2)
// unchanged from R7.

#define NPB     16
#define BLOCK   256
#define D       128
#define CHUNK   512
#define ASTRIDE 136   // agg_s row stride in shorts (128 + 8 pad)

typedef __attribute__((ext_vector_type(8))) short bf16x8;
typedef __attribute__((ext_vector_type(4))) float f32x4;

__device__ __forceinline__ short f2bf(float f) {
    unsigned u = __float_as_uint(f);
    unsigned r = (u + 0x7fffu + ((u >> 16) & 1u)) >> 16;
    return (short)r;
}
__device__ __forceinline__ float bf_lo(int w) { return __int_as_float(w << 16); }
__device__ __forceinline__ float bf_hi(int w) { return __int_as_float(w & 0xffff0000); }

// ---------------- prepass: rs build + x->bf16 + W->bf16 ----------------
// ids [0, n_nodes]: one lower_bound each (latency chains, first in grid so
// they overlap the streaming cvt); next n4 ids: x float4->bf16; last nw4 ids:
// W float4->bf16.
__global__ __launch_bounds__(256)
void prepass_kernel(const float* __restrict__ x,
                    const float* __restrict__ W,
                    const int*   __restrict__ edge_row,
                    short* __restrict__ xb,
                    short* __restrict__ wb,
                    int*   __restrict__ rs,
                    int n_nodes, int n_edges, int n4, int nw4)
{
    const int gid = blockIdx.x * 256 + threadIdx.x;

    if (gid <= n_nodes) {
        int lo = 0, hi = n_edges;
        while (lo < hi) {
            int mid = (lo + hi) >> 1;
            bool lt = (edge_row[mid] < gid);
            lo = lt ? (mid + 1) : lo;
            hi = lt ? hi : mid;
        }
        rs[gid] = lo;
    }

    const int i = gid - (n_nodes + 1);
    if (i >= 0 && i < n4) {
        float4 v = reinterpret_cast<const float4*>(x)[i];
        reinterpret_cast<short4*>(xb)[i] =
            make_short4(f2bf(v.x), f2bf(v.y), f2bf(v.z), f2bf(v.w));
    }

    const int iw = i - n4;
    if (iw >= 0 && iw < nw4) {
        float4 v = reinterpret_cast<const float4*>(W)[iw];
        reinterpret_cast<short4*>(wb)[iw] =
            make_short4(f2bf(v.x), f2bf(v.y), f2bf(v.z), f2bf(v.w));
    }
}

// ---------------- main kernel ----------------
__global__ __launch_bounds__(BLOCK, 8)
void gcn_main_kernel(const short* __restrict__ xb,
                     const short* __restrict__ wb,
                     const int*   __restrict__ rs_g,
                     const int*   __restrict__ edge_col,
                     const float* __restrict__ edge_val,
                     const float* __restrict__ bvec,
                     float*       __restrict__ out,
                     int n_nodes, int n_edges)
{
    __shared__ int2  cv_s[CHUNK];                          // 4 KB
    __shared__ __align__(16) short agg_s[NPB * ASTRIDE];   // 4.25 KB bf16
    __shared__ int rs_s[NPB + 1];

    const int tid  = threadIdx.x;
    const int wave = tid >> 6;
    const int lane = tid & 63;
    const int tile_base = blockIdx.x * NPB;

    // ---- Phase 0: load precomputed row starts ----
    if (tid <= NPB) rs_s[tid] = rs_g[tile_base + tid];
    __syncthreads();

    const int E0 = __builtin_amdgcn_readfirstlane(rs_s[0]);
    const int E1 = __builtin_amdgcn_readfirstlane(rs_s[NPB]);

    // ---- Phase 1: quarter-wave-per-node bf16 SpMM ----
    const int p = lane >> 4;            // quarter-wave id -> node within wave
    const int q = lane & 15;            // feature oct (8 bf16 = 16 B)
    const int n = wave * 4 + p;         // node within tile
    const int e0 = rs_s[n], e1 = rs_s[n + 1];
    const short* xq = xb + q * 8;

    float2 acc2[4];
    #pragma unroll
    for (int i = 0; i < 4; ++i) acc2[i] = make_float2(0.f, 0.f);

    for (int cb = E0; cb < E1; cb += CHUNK) {
        const int cnt = min(E1 - cb, CHUNK);
        __syncthreads();                // protect cv_s across chunks
        for (int i = tid; i < cnt; i += BLOCK) {
            cv_s[i] = make_int2(edge_col[cb + i], __float_as_int(edge_val[cb + i]));
        }
        __syncthreads();

        const int s = max(e0, cb);
        const int t = min(e1, cb + cnt);
        int m = t - s;
        int mm = max(m, __shfl_xor(m, 16, 64));
        mm = max(mm, __shfl_xor(mm, 32, 64));
        mm = __builtin_amdgcn_readfirstlane(mm);

        for (int it = 0; it < mm; it += 8) {
            #pragma unroll
            for (int u = 0; u < 8; ++u) {
                int idx = s + it + u;
                bool ok = (idx < t);
                int il = ok ? (idx - cb) : 0;
                int2 cv = cv_s[il];
                float v = ok ? __int_as_float(cv.y) : 0.f;
                int4 xr = *reinterpret_cast<const int4*>(xq + ((size_t)cv.x << 7));
                float2 p0 = make_float2(bf_lo(xr.x), bf_hi(xr.x));
                float2 p1 = make_float2(bf_lo(xr.y), bf_hi(xr.y));
                float2 p2 = make_float2(bf_lo(xr.z), bf_hi(xr.z));
                float2 p3 = make_float2(bf_lo(xr.w), bf_hi(xr.w));
                acc2[0].x = fmaf(v, p0.x, acc2[0].x); acc2[0].y = fmaf(v, p0.y, acc2[0].y);
                acc2[1].x = fmaf(v, p1.x, acc2[1].x); acc2[1].y = fmaf(v, p1.y, acc2[1].y);
                acc2[2].x = fmaf(v, p2.x, acc2[2].x); acc2[2].y = fmaf(v, p2.y, acc2[2].y);
                acc2[3].x = fmaf(v, p3.x, acc2[3].x); acc2[3].y = fmaf(v, p3.y, acc2[3].y);
            }
        }
    }

    // store agg row segment (lane owns node n, features 8q..8q+7)
    {
        bf16x8 o;
        o[0] = f2bf(acc2[0].x); o[1] = f2bf(acc2[0].y);
        o[2] = f2bf(acc2[1].x); o[3] = f2bf(acc2[1].y);
        o[4] = f2bf(acc2[2].x); o[5] = f2bf(acc2[2].y);
        o[6] = f2bf(acc2[3].x); o[7] = f2bf(acc2[3].y);
        *reinterpret_cast<bf16x8*>(&agg_s[n * ASTRIDE + q * 8]) = o;
    }

    // ---- B-fragment load (bf16 W from ws, direct 16-B loads) + bias,
    //      issued before the barrier so latency overlaps the wait ----
    const int n16 = lane & 15;
    const int g   = lane >> 4;

    bf16x8 bfr[2][4];
    float  bj[2];
    #pragma unroll
    for (int tt = 0; tt < 2; ++tt) {
        const int jt = 2 * wave + tt;
        const short* wrow = wb + ((size_t)(jt * 16 + n16)) * D + g * 8;
        #pragma unroll
        for (int ks = 0; ks < 4; ++ks) {
            bfr[tt][ks] = *reinterpret_cast<const bf16x8*>(wrow + ks * 32);
        }
        bj[tt] = bvec[jt * 16 + n16];
    }

    __syncthreads();

    // ---- Phase 2: out = agg @ W^T + b via MFMA (layout verified R5-R7) ----
    {
        bf16x8 afr[4];
        #pragma unroll
        for (int ks = 0; ks < 4; ++ks) {
            afr[ks] = *reinterpret_cast<const bf16x8*>(
                &agg_s[n16 * ASTRIDE + ks * 32 + g * 8]);
        }

        #pragma unroll
        for (int tt = 0; tt < 2; ++tt) {
            const int jt = 2 * wave + tt;
            const int j  = jt * 16 + n16;

            f32x4 c = {0.f, 0.f, 0.f, 0.f};
            #pragma unroll
            for (int ks = 0; ks < 4; ++ks) {
                c = __builtin_amdgcn_mfma_f32_16x16x32_bf16(afr[ks], bfr[tt][ks], c, 0, 0, 0);
            }
            #pragma unroll
            for (int r = 0; r < 4; ++r) {
                int node = tile_base + g * 4 + r;
                if (node < n_nodes)
                    out[(size_t)node * D + j] = c[r] + bj[tt];
            }
        }
    }
}

// ---------------- fallback (R5 kernel, fp32 gathers, no ws) ----------------
__global__ __launch_bounds__(BLOCK, 5)
void gcn_fallback_kernel(const float* __restrict__ x,
                         const int*   __restrict__ edge_row,
                         const int*   __restrict__ edge_col,
                         const float* __restrict__ edge_val,
                         const float* __restrict__ W,
                         const float* __restrict__ bvec,
                         float*       __restrict__ out,
                         int n_nodes, int n_edges)
{
    __shared__ __align__(16) short agg_s[NPB * ASTRIDE];
    __shared__ int rs_s[NPB + 1];

    const int tid  = threadIdx.x;
    const int wave = tid >> 6;
    const int lane = tid & 63;
    const int tile_base = blockIdx.x * NPB;

    if (tid <= NPB) {
        int target = tile_base + tid;
        if (target > n_nodes) target = n_nodes;
        int lo = 0, hi = n_edges;
        while (lo < hi) {
            int mid = (lo + hi) >> 1;
            lo = (edge_row[mid] < target) ? (mid + 1) : lo;
            hi = (edge_row[mid] < target) ? hi : mid;
        }
        rs_s[tid] = lo;
    }
    __syncthreads();

    {
        const int h = lane >> 5;
        const int q = lane & 31;
        const float* xq = x + (q << 2);

        #pragma unroll
        for (int ni = 0; ni < NPB / 4; ++ni) {
            const int n = wave + 4 * ni;
            const int e0 = __builtin_amdgcn_readfirstlane(rs_s[n]);
            const int e1 = __builtin_amdgcn_readfirstlane(rs_s[n + 1]);
            float ax = 0.f, ay = 0.f, az = 0.f, aw = 0.f;
            for (int e = e0; e < e1; e += 16) {
                #pragma unroll
                for (int u = 0; u < 8; ++u) {
                    int idx  = e + 2 * u + h;
                    int idxc = (idx < e1) ? idx : (e1 - 1);
                    int   c  = edge_col[idxc];
                    float vr = edge_val[idxc];
                    float v  = (idx < e1) ? vr : 0.f;
                    float4 xr = *reinterpret_cast<const float4*>(xq + ((size_t)c << 7));
                    ax += v * xr.x; ay += v * xr.y; az += v * xr.z; aw += v * xr.w;
                }
            }
            ax += __shfl_xor(ax, 32, 64); ay += __shfl_xor(ay, 32, 64);
            az += __shfl_xor(az, 32, 64); aw += __shfl_xor(aw, 32, 64);
            if (h == 0) {
                *reinterpret_cast<short4*>(&agg_s[n * ASTRIDE + (q << 2)]) =
                    make_short4(f2bf(ax), f2bf(ay), f2bf(az), f2bf(aw));
            }
        }
    }

    const int n16 = lane & 15;
    const int g   = lane >> 4;
    bf16x8 bfr[2][4];
    #pragma unroll
    for (int tt = 0; tt < 2; ++tt) {
        const int jt = 2 * wave + tt;
        const float* rowp = W + ((size_t)(jt * 16 + n16)) * D + g * 8;
        #pragma unroll
        for (int ks = 0; ks < 4; ++ks) {
            float4 wa = *reinterpret_cast<const float4*>(rowp + ks * 32);
            float4 wb4 = *reinterpret_cast<const float4*>(rowp + ks * 32 + 4);
            bf16x8 f;
            f[0] = f2bf(wa.x); f[1] = f2bf(wa.y); f[2] = f2bf(wa.z); f[3] = f2bf(wa.w);
            f[4] = f2bf(wb4.x); f[5] = f2bf(wb4.y); f[6] = f2bf(wb4.z); f[7] = f2bf(wb4.w);
            bfr[tt][ks] = f;
        }
    }
    __syncthreads();
    {
        bf16x8 afr[4];
        #pragma unroll
        for (int ks = 0; ks < 4; ++ks)
            afr[ks] = *reinterpret_cast<const bf16x8*>(&agg_s[n16 * ASTRIDE + ks * 32 + g * 8]);
        #pragma unroll
        for (int tt = 0; tt < 2; ++tt) {
            const int jt = 2 * wave + tt;
            const int j  = jt * 16 + n16;
            const float bj = bvec[j];
            f32x4 c = {0.f, 0.f, 0.f, 0.f};
            #pragma unroll
            for (int ks = 0; ks < 4; ++ks)
                c = __builtin_amdgcn_mfma_f32_16x16x32_bf16(afr[ks], bfr[tt][ks], c, 0, 0, 0);
            #pragma unroll
            for (int r = 0; r < 4; ++r) {
                int node = tile_base + g * 4 + r;
                if (node < n_nodes)
                    out[(size_t)node * D + j] = c[r] + bj;
            }
        }
    }
}

extern "C" void kernel_launch(void* const* d_in, const int* in_sizes, int n_in,
                              void* d_out, int out_size, void* d_ws, size_t ws_size,
                              hipStream_t stream) {
    const float* x        = (const float*)d_in[0];
    const int*   edge_row = (const int*)  d_in[1];
    const int*   edge_col = (const int*)  d_in[2];
    const float* edge_val = (const float*)d_in[3];
    const float* W        = (const float*)d_in[4];
    const float* b        = (const float*)d_in[5];
    float* out = (float*)d_out;

    const int n_nodes = in_sizes[0] / D;
    const int n_edges = in_sizes[1];
    const int grid = (n_nodes + NPB - 1) / NPB;

    const size_t xb_bytes = (size_t)n_nodes * D * sizeof(short);
    const size_t rs_bytes = (size_t)(n_nodes + 1) * sizeof(int);
    const size_t wb_bytes = (size_t)D * D * sizeof(short);
    if (ws_size >= xb_bytes + rs_bytes + wb_bytes) {
        short* xb = (short*)d_ws;
        int*   rs = (int*)((char*)d_ws + xb_bytes);
        short* wb = (short*)((char*)d_ws + xb_bytes + rs_bytes);
        const int n4  = n_nodes * D / 4;
        const int nw4 = D * D / 4;
        const int total = (n_nodes + 1) + n4 + nw4;
        prepass_kernel<<<(total + 255) / 256, 256, 0, stream>>>(
            x, W, edge_row, xb, wb, rs, n_nodes, n_edges, n4, nw4);
        gcn_main_kernel<<<grid, BLOCK, 0, stream>>>(xb, wb, rs, edge_col, edge_val,
                                                    b, out, n_nodes, n_edges);
    } else {
        gcn_fallback_kernel<<<grid, BLOCK, 0, stream>>>(x, edge_row, edge_col, edge_val,
                                                        W, b, out, n_nodes, n_edges);
    }
}

// Round 9
// 122.429 us; speedup vs baseline: 15.5012x; 1.0450x over previous
//
#include <hip/hip_runtime.h>
#include <hip/hip_bf16.h>

// GCN layer, fused: out[i][j] = b[j] + sum_k ( sum_{e: row[e]==i} val[e]*x[col[e]][k] ) * W[j][k]
// N=50000 nodes, E=800000 edges (row sorted), D_IN=D_OUT=128, fp32 in/out.
//
// R9 changes vs R8 (theory: VGPR=40 proves the compiler serialized the 8-deep
// gather batch to ~4; per-chunk barriers + mm machinery are pure overhead since
// a 16-node tile's degree (~Poisson(256)) never exceeds one 512 chunk):
//   - Explicit three-stage batch (8 cv ds_reads -> 8 gathers -> math) to force
//     8 loads in flight; __launch_bounds__(256,6) gives the VGPR room (~85).
//   - Edge range staged ONCE per block (cold global slow-path if degree>512);
//     no per-chunk barriers, no shfl-max; per-quarter-wave loop bound.
//   - float2 accumulate (v_pk_fma_f32 candidate): 4 packed FMA per edge-lane.
// Prepass (rs + x->bf16 + W->bf16) and MFMA phase 2 unchanged.

#define NPB     16
#define BLOCK   256
#define D       128
#define CHUNK   512
#define ASTRIDE 136   // agg_s row stride in shorts (128 + 8 pad)

typedef __attribute__((ext_vector_type(8))) short bf16x8;
typedef __attribute__((ext_vector_type(4))) float f32x4;
typedef __attribute__((ext_vector_type(2))) float v2f;

__device__ __forceinline__ short f2bf(float f) {
    unsigned u = __float_as_uint(f);
    unsigned r = (u + 0x7fffu + ((u >> 16) & 1u)) >> 16;
    return (short)r;
}
__device__ __forceinline__ float bf_lo(int w) { return __int_as_float(w << 16); }
__device__ __forceinline__ float bf_hi(int w) { return __int_as_float(w & 0xffff0000); }

// ---------------- prepass: rs build + x->bf16 + W->bf16 ----------------
__global__ __launch_bounds__(256)
void prepass_kernel(const float* __restrict__ x,
                    const float* __restrict__ W,
                    const int*   __restrict__ edge_row,
                    short* __restrict__ xb,
                    short* __restrict__ wb,
                    int*   __restrict__ rs,
                    int n_nodes, int n_edges, int n4, int nw4)
{
    const int gid = blockIdx.x * 256 + threadIdx.x;

    if (gid <= n_nodes) {
        int lo = 0, hi = n_edges;
        while (lo < hi) {
            int mid = (lo + hi) >> 1;
            bool lt = (edge_row[mid] < gid);
            lo = lt ? (mid + 1) : lo;
            hi = lt ? hi : mid;
        }
        rs[gid] = lo;
    }

    const int i = gid - (n_nodes + 1);
    if (i >= 0 && i < n4) {
        float4 v = reinterpret_cast<const float4*>(x)[i];
        reinterpret_cast<short4*>(xb)[i] =
            make_short4(f2bf(v.x), f2bf(v.y), f2bf(v.z), f2bf(v.w));
    }

    const int iw = i - n4;
    if (iw >= 0 && iw < nw4) {
        float4 v = reinterpret_cast<const float4*>(W)[iw];
        reinterpret_cast<short4*>(wb)[iw] =
            make_short4(f2bf(v.x), f2bf(v.y), f2bf(v.z), f2bf(v.w));
    }
}

// ---------------- main kernel ----------------
__global__ __launch_bounds__(BLOCK, 6)
void gcn_main_kernel(const short* __restrict__ xb,
                     const short* __restrict__ wb,
                     const int*   __restrict__ rs_g,
                     const int*   __restrict__ edge_col,
                     const float* __restrict__ edge_val,
                     const float* __restrict__ bvec,
                     float*       __restrict__ out,
                     int n_nodes, int n_edges)
{
    __shared__ int2  cv_s[CHUNK];                          // 4 KB
    __shared__ __align__(16) short agg_s[NPB * ASTRIDE];   // 4.25 KB bf16
    __shared__ int rs_s[NPB + 1];

    const int tid  = threadIdx.x;
    const int wave = tid >> 6;
    const int lane = tid & 63;
    const int tile_base = blockIdx.x * NPB;

    // ---- Phase 0: row starts (one coalesced read) ----
    if (tid <= NPB) rs_s[tid] = rs_g[tile_base + tid];
    __syncthreads();

    const int E0 = __builtin_amdgcn_readfirstlane(rs_s[0]);
    const int E1 = __builtin_amdgcn_readfirstlane(rs_s[NPB]);
    const int cnt = min(E1 - E0, CHUNK);

    // ---- stage the block's edge range once (tile degree ~256, <512 w.h.p.) ----
    for (int i = tid; i < cnt; i += BLOCK) {
        cv_s[i] = make_int2(edge_col[E0 + i], __float_as_int(edge_val[E0 + i]));
    }
    __syncthreads();

    // ---- Phase 1: quarter-wave-per-node bf16 SpMM, forced 8-deep batches ----
    const int p = lane >> 4;            // quarter-wave id -> node within wave
    const int q = lane & 15;            // feature oct (8 bf16 = 16 B)
    const int n = wave * 4 + p;         // node within tile
    const int e0 = rs_s[n], e1 = rs_s[n + 1];
    const int cap  = E0 + cnt;          // staged range end
    const int ecap = min(e1, cap);
    const short* xq = xb + q * 8;

    v2f acc2[4];
    #pragma unroll
    for (int i = 0; i < 4; ++i) acc2[i] = (v2f){0.f, 0.f};

    for (int e = e0; e < ecap; e += 8) {
        int2  cv[8];
        int4  xr[8];
        // stage 1: 8 LDS metadata reads (broadcast within quarter-wave)
        #pragma unroll
        for (int u = 0; u < 8; ++u) {
            int idx = e + u;
            int il  = (idx < ecap) ? (idx - E0) : (e0 - E0);
            cv[u] = cv_s[il];
        }
        // stage 2: 8 gathers in flight
        #pragma unroll
        for (int u = 0; u < 8; ++u) {
            xr[u] = *reinterpret_cast<const int4*>(xq + ((size_t)cv[u].x << 7));
        }
        // stage 3: math (packed float2 FMA)
        #pragma unroll
        for (int u = 0; u < 8; ++u) {
            float vm = (e + u < ecap) ? __int_as_float(cv[u].y) : 0.f;
            v2f v2 = (v2f){vm, vm};
            acc2[0] += v2 * (v2f){bf_lo(xr[u].x), bf_hi(xr[u].x)};
            acc2[1] += v2 * (v2f){bf_lo(xr[u].y), bf_hi(xr[u].y)};
            acc2[2] += v2 * (v2f){bf_lo(xr[u].z), bf_hi(xr[u].z)};
            acc2[3] += v2 * (v2f){bf_lo(xr[u].w), bf_hi(xr[u].w)};
        }
    }
    // cold slow path: only if this tile's degree exceeded CHUNK (never for
    // the benchmark's random graph; kept for correctness)
    for (int e = max(e0, cap); e < e1; ++e) {
        int   c = edge_col[e];
        float v = edge_val[e];
        int4 xr = *reinterpret_cast<const int4*>(xq + ((size_t)c << 7));
        v2f v2 = (v2f){v, v};
        acc2[0] += v2 * (v2f){bf_lo(xr.x), bf_hi(xr.x)};
        acc2[1] += v2 * (v2f){bf_lo(xr.y), bf_hi(xr.y)};
        acc2[2] += v2 * (v2f){bf_lo(xr.z), bf_hi(xr.z)};
        acc2[3] += v2 * (v2f){bf_lo(xr.w), bf_hi(xr.w)};
    }

    // store agg row segment (lane owns node n, features 8q..8q+7)
    {
        bf16x8 o;
        o[0] = f2bf(acc2[0].x); o[1] = f2bf(acc2[0].y);
        o[2] = f2bf(acc2[1].x); o[3] = f2bf(acc2[1].y);
        o[4] = f2bf(acc2[2].x); o[5] = f2bf(acc2[2].y);
        o[6] = f2bf(acc2[3].x); o[7] = f2bf(acc2[3].y);
        *reinterpret_cast<bf16x8*>(&agg_s[n * ASTRIDE + q * 8]) = o;
    }

    // ---- B-fragment + bias loads (bf16 W from ws), before the barrier ----
    const int n16 = lane & 15;
    const int g   = lane >> 4;

    bf16x8 bfr[2][4];
    float  bj[2];
    #pragma unroll
    for (int tt = 0; tt < 2; ++tt) {
        const int jt = 2 * wave + tt;
        const short* wrow = wb + ((size_t)(jt * 16 + n16)) * D + g * 8;
        #pragma unroll
        for (int ks = 0; ks < 4; ++ks) {
            bfr[tt][ks] = *reinterpret_cast<const bf16x8*>(wrow + ks * 32);
        }
        bj[tt] = bvec[jt * 16 + n16];
    }

    __syncthreads();

    // ---- Phase 2: out = agg @ W^T + b via MFMA (layout verified R5-R8) ----
    {
        bf16x8 afr[4];
        #pragma unroll
        for (int ks = 0; ks < 4; ++ks) {
            afr[ks] = *reinterpret_cast<const bf16x8*>(
                &agg_s[n16 * ASTRIDE + ks * 32 + g * 8]);
        }

        #pragma unroll
        for (int tt = 0; tt < 2; ++tt) {
            const int jt = 2 * wave + tt;
            const int j  = jt * 16 + n16;

            f32x4 c = {0.f, 0.f, 0.f, 0.f};
            #pragma unroll
            for (int ks = 0; ks < 4; ++ks) {
                c = __builtin_amdgcn_mfma_f32_16x16x32_bf16(afr[ks], bfr[tt][ks], c, 0, 0, 0);
            }
            #pragma unroll
            for (int r = 0; r < 4; ++r) {
                int node = tile_base + g * 4 + r;
                if (node < n_nodes)
                    out[(size_t)node * D + j] = c[r] + bj[tt];
            }
        }
    }
}

// ---------------- fallback (R5 kernel, fp32 gathers, no ws) ----------------
__global__ __launch_bounds__(BLOCK, 5)
void gcn_fallback_kernel(const float* __restrict__ x,
                         const int*   __restrict__ edge_row,
                         const int*   __restrict__ edge_col,
                         const float* __restrict__ edge_val,
                         const float* __restrict__ W,
                         const float* __restrict__ bvec,
                         float*       __restrict__ out,
                         int n_nodes, int n_edges)
{
    __shared__ __align__(16) short agg_s[NPB * ASTRIDE];
    __shared__ int rs_s[NPB + 1];

    const int tid  = threadIdx.x;
    const int wave = tid >> 6;
    const int lane = tid & 63;
    const int tile_base = blockIdx.x * NPB;

    if (tid <= NPB) {
        int target = tile_base + tid;
        if (target > n_nodes) target = n_nodes;
        int lo = 0, hi = n_edges;
        while (lo < hi) {
            int mid = (lo + hi) >> 1;
            lo = (edge_row[mid] < target) ? (mid + 1) : lo;
            hi = (edge_row[mid] < target) ? hi : mid;
        }
        rs_s[tid] = lo;
    }
    __syncthreads();

    {
        const int h = lane >> 5;
        const int q = lane & 31;
        const float* xq = x + (q << 2);

        #pragma unroll
        for (int ni = 0; ni < NPB / 4; ++ni) {
            const int n = wave + 4 * ni;
            const int e0 = __builtin_amdgcn_readfirstlane(rs_s[n]);
            const int e1 = __builtin_amdgcn_readfirstlane(rs_s[n + 1]);
            float ax = 0.f, ay = 0.f, az = 0.f, aw = 0.f;
            for (int e = e0; e < e1; e += 16) {
                #pragma unroll
                for (int u = 0; u < 8; ++u) {
                    int idx  = e + 2 * u + h;
                    int idxc = (idx < e1) ? idx : (e1 - 1);
                    int   c  = edge_col[idxc];
                    float vr = edge_val[idxc];
                    float v  = (idx < e1) ? vr : 0.f;
                    float4 xr = *reinterpret_cast<const float4*>(xq + ((size_t)c << 7));
                    ax += v * xr.x; ay += v * xr.y; az += v * xr.z; aw += v * xr.w;
                }
            }
            ax += __shfl_xor(ax, 32, 64); ay += __shfl_xor(ay, 32, 64);
            az += __shfl_xor(az, 32, 64); aw += __shfl_xor(aw, 32, 64);
            if (h == 0) {
                *reinterpret_cast<short4*>(&agg_s[n * ASTRIDE + (q << 2)]) =
                    make_short4(f2bf(ax), f2bf(ay), f2bf(az), f2bf(aw));
            }
        }
    }

    const int n16 = lane & 15;
    const int g   = lane >> 4;
    bf16x8 bfr[2][4];
    #pragma unroll
    for (int tt = 0; tt < 2; ++tt) {
        const int jt = 2 * wave + tt;
        const float* rowp = W + ((size_t)(jt * 16 + n16)) * D + g * 8;
        #pragma unroll
        for (int ks = 0; ks < 4; ++ks) {
            float4 wa  = *reinterpret_cast<const float4*>(rowp + ks * 32);
            float4 wb4 = *reinterpret_cast<const float4*>(rowp + ks * 32 + 4);
            bf16x8 f;
            f[0] = f2bf(wa.x);  f[1] = f2bf(wa.y);  f[2] = f2bf(wa.z);  f[3] = f2bf(wa.w);
            f[4] = f2bf(wb4.x); f[5] = f2bf(wb4.y); f[6] = f2bf(wb4.z); f[7] = f2bf(wb4.w);
            bfr[tt][ks] = f;
        }
    }
    __syncthreads();
    {
        bf16x8 afr[4];
        #pragma unroll
        for (int ks = 0; ks < 4; ++ks)
            afr[ks] = *reinterpret_cast<const bf16x8*>(&agg_s[n16 * ASTRIDE + ks * 32 + g * 8]);
        #pragma unroll
        for (int tt = 0; tt < 2; ++tt) {
            const int jt = 2 * wave + tt;
            const int j  = jt * 16 + n16;
            const float bj = bvec[j];
            f32x4 c = {0.f, 0.f, 0.f, 0.f};
            #pragma unroll
            for (int ks = 0; ks < 4; ++ks)
                c = __builtin_amdgcn_mfma_f32_16x16x32_bf16(afr[ks], bfr[tt][ks], c, 0, 0, 0);
            #pragma unroll
            for (int r = 0; r < 4; ++r) {
                int node = tile_base + g * 4 + r;
                if (node < n_nodes)
                    out[(size_t)node * D + j] = c[r] + bj;
            }
        }
    }
}

extern "C" void kernel_launch(void* const* d_in, const int* in_sizes, int n_in,
                              void* d_out, int out_size, void* d_ws, size_t ws_size,
                              hipStream_t stream) {
    const float* x        = (const float*)d_in[0];
    const int*   edge_row = (const int*)  d_in[1];
    const int*   edge_col = (const int*)  d_in[2];
    const float* edge_val = (const float*)d_in[3];
    const float* W        = (const float*)d_in[4];
    const float* b        = (const float*)d_in[5];
    float* out = (float*)d_out;

    const int n_nodes = in_sizes[0] / D;
    const int n_edges = in_sizes[1];
    const int grid = (n_nodes + NPB - 1) / NPB;

    const size_t xb_bytes = (size_t)n_nodes * D * sizeof(short);
    const size_t rs_bytes = (size_t)(n_nodes + 1) * sizeof(int);
    const size_t wb_bytes = (size_t)D * D * sizeof(short);
    if (ws_size >= xb_bytes + rs_bytes + wb_bytes) {
        short* xb = (short*)d_ws;
        int*   rs = (int*)((char*)d_ws + xb_bytes);
        short* wb = (short*)((char*)d_ws + xb_bytes + rs_bytes);
        const int n4  = n_nodes * D / 4;
        const int nw4 = D * D / 4;
        const int total = (n_nodes + 1) + n4 + nw4;
        prepass_kernel<<<(total + 255) / 256, 256, 0, stream>>>(
            x, W, edge_row, xb, wb, rs, n_nodes, n_edges, n4, nw4);
        gcn_main_kernel<<<grid, BLOCK, 0, stream>>>(xb, wb, rs, edge_col, edge_val,
                                                    b, out, n_nodes, n_edges);
    } else {
        gcn_fallback_kernel<<<grid, BLOCK, 0, stream>>>(x, edge_row, edge_col, edge_val,
                                                        W, b, out, n_nodes, n_edges);
    }
}